// Round 8
// baseline (163.006 us; speedup 1.0000x reference)
//
#include <hip/hip_runtime.h>
#include <hip/hip_bf16.h>

// Locally-connected conv, ALL FP32 in/out, bf16 MFMA compute.
//   x:   (32, 16, 64, 64)        float
//   w:   (60, 60, 16, 5, 5, 16)  float   (per-position 400x16, k innermost)
//   out: (32, 16, 60, 60)        float
//
// Round-8: software-pipelined W DMA across positions.
//  * Block = 5 consecutive j positions (720 blocks x 128 thr); W DMA
//    double-buffered: DMA(p+1) issued right after barrier(p), in flight
//    during compute(p)+store(p) -> each block keeps a 25.6 KB transfer
//    outstanding continuously (fixes the r6/r7 drain-then-silent bubble).
//  * Direct store of each wave's 16x16 D-tile to out (transpose_out and
//    the ws out-buffer deleted); XCD swizzle gives each XCD a contiguous
//    j-band so L2 write-merges the 20B/line this block produces.
//  * W staged via __builtin_amdgcn_global_load_lds width=16 (no scratch).
//  * B-frag: 8x ds_read_b32 from raw [m][k] LDS (2-way banks = free) + pack.

#define OUT_HW 60
#define IN_HW  64
#define CIN    16
#define COUT   16
#define NPOS   3600              // OUT_HW*OUT_HW
#define T_J    5                 // j positions per block
#define NTILE  720               // 60 rows x 12 j-tiles
#define XC_ELE (32u * 64u * 64u * 16u)   // 2,097,152 bf16 elements

typedef __attribute__((ext_vector_type(8))) short bf16x8;
typedef __attribute__((ext_vector_type(4))) float f32x4;

static __device__ __forceinline__ unsigned pk2(float a, float b) {
    union { __hip_bfloat162 h; unsigned u; } cv;
    cv.h = __float22bfloat162_rn(make_float2(a, b));
    return cv.u;
}

// async global->LDS, 16B per lane; LDS dest wave-uniform, src per-lane.
static __device__ __forceinline__ void g2lds16(const float* g, float* l) {
    __builtin_amdgcn_global_load_lds(
        (const __attribute__((address_space(1))) unsigned int*)g,
        (__attribute__((address_space(3))) unsigned int*)l, 16, 0, 0);
}

// ---- prepass: xc[b][h][w][c] bf16 <- x[b][c][h][w] fp32 (proven r5-r7) ----
__global__ __launch_bounds__(256)
void make_xc(const float* __restrict__ x, ushort* __restrict__ xc) {
    const int bh = blockIdx.x;               // b*64 + h
    const int b = bh >> 6, h = bh & 63;
    const int t = threadIdx.x;
    const int cq = t & 3, wc = t >> 2;
    const float* src = x + ((size_t)(b * CIN) * IN_HW + h) * IN_HW + wc;
    float f[4];
#pragma unroll
    for (int e = 0; e < 4; ++e)
        f[e] = src[(size_t)(cq * 4 + e) * (IN_HW * IN_HW)];
    union { ushort4 v; unsigned u[2]; } o;
    o.u[0] = pk2(f[0], f[1]);
    o.u[1] = pk2(f[2], f[3]);
    *(ushort4*)&xc[((size_t)bh * IN_HW + wc) * CIN + cq * 4] = o.v;
}

// ---- main: 720 blocks x 128 thr; block = row i, j-tile of 5 positions ----
__global__ __launch_bounds__(128)
void lc_pos(const ushort* __restrict__ xc, const float* __restrict__ w,
            float* __restrict__ out) {
    __shared__ float sW[2][6400] __attribute__((aligned(16)));  // 51,200 B dbuf

    const int bid = blockIdx.x;
    const int tt  = (bid & 7) * 90 + (bid >> 3);     // XCD swizzle (bijective, 720)
    const int i   = tt / 12, jt = tt - i * 12;
    const int j0  = jt * T_J;
    const int t = threadIdx.x;
    const int lane = t & 63, wv = t >> 6;            // wv = b-tile (M-split)
    const int l15 = lane & 15, q = lane >> 4;
    const int qh = q >> 1, c0 = (q & 1) << 3;

    const float* wbase = w + (size_t)(i * OUT_HW + j0) * 6400 + lane * 4;
    const size_t bofs  = (size_t)(wv * 16 + l15) * (IN_HW * IN_HW * CIN);

    // ---- DMA(0): 25 x (64 lanes x 16B) = 25,600 B ----
    for (int o = wv; o < 25; o += 2)
        g2lds16(wbase + o * 256, &sW[0][o * 256]);

    for (int p = 0; p < T_J; ++p) {
        // ---- prefetch this position's 13 A-fragments (overlaps DMA(p)) ----
        const int base_hw = i * IN_HW + (j0 + p);
        bf16x8 xa[13];
#pragma unroll
        for (int cc = 0; cc < 13; ++cc) {
            const int uvB = cc * 2 + qh;
            const int uvA = (uvB < 25) ? uvB : 24;   // clamped; W=0 there
            const int uA = (uvA * 13) >> 6;          // uv/5 for uv<=24
            const int vA = uvA - 5 * uA;
            xa[cc] = *(const bf16x8*)(xc + bofs
                       + (size_t)(base_hw + uA * IN_HW + vA) * CIN + c0);
        }

        __syncthreads();   // drains DMA(p) + A-prefetch; fences compute(p-1)

        // ---- issue DMA(p+1) into the other buffer (overlaps compute(p)) ----
        if (p + 1 < T_J) {
            const float* wn = wbase + (size_t)(p + 1) * 6400;
            float* ld = &sW[(p + 1) & 1][0];
            for (int o = wv; o < 25; o += 2)
                g2lds16(wn + o * 256, ld + o * 256);
        }

        // ---- MFMA: k_r=(uv,c), c innermost; 13 chunks ----
        const float* sWb = &sW[p & 1][0];
        f32x4 acc = {0.f, 0.f, 0.f, 0.f};
#pragma unroll
        for (int cc = 0; cc < 13; ++cc) {
            const int uvB = cc * 2 + qh;
            const int okB = (uvB < 25);
            float bfv[8];
#pragma unroll
            for (int jj = 0; jj < 8; ++jj)       // m = (c0+jj)*25 + uvB, k = l15
                bfv[jj] = okB ? sWb[(c0 + jj) * 400 + uvB * 16 + l15] : 0.f;
            union { bf16x8 v; unsigned u[4]; } pb;
#pragma unroll
            for (int jj = 0; jj < 4; ++jj) pb.u[jj] = pk2(bfv[2 * jj], bfv[2 * jj + 1]);
            acc = __builtin_amdgcn_mfma_f32_16x16x32_bf16(xa[cc], pb.v, acc, 0, 0, 0);
        }

        // ---- direct store: rows b = wv*16 + q*4 + r, col k = l15 ----
#pragma unroll
        for (int r = 0; r < 4; ++r) {
            const int b = wv * 16 + q * 4 + r;
            out[(size_t)(b * COUT + l15) * NPOS + i * OUT_HW + (j0 + p)] = acc[r];
        }
    }
}

// ---- emergency fallback (ws too small): naive, correct, slow ----
__global__ __launch_bounds__(256)
void lc_naive(const float* __restrict__ x, const float* __restrict__ w,
              float* __restrict__ out) {
    const int gid = blockIdx.x * 256 + threadIdx.x;
    if (gid >= 32 * COUT * NPOS) return;
    const int j = gid % OUT_HW;
    int rest = gid / OUT_HW;
    const int i = rest % OUT_HW; rest /= OUT_HW;
    const int k = rest % COUT;
    const int b = rest / COUT;
    const float* wp = w + (size_t)(i * OUT_HW + j) * 6400 + k;
    float s = 0.f;
    for (int c = 0; c < CIN; ++c)
        for (int u = 0; u < 5; ++u)
            for (int v = 0; v < 5; ++v)
                s += x[((size_t)(b * CIN + c) * IN_HW + i + u) * IN_HW + j + v]
                   * wp[((c * 5 + u) * 5 + v) * COUT];
    out[gid] = s;
}

extern "C" void kernel_launch(void* const* d_in, const int* in_sizes, int n_in,
                              void* d_out, int out_size, void* d_ws, size_t ws_size,
                              hipStream_t stream) {
    const float* x = (const float*)d_in[0];
    const float* w = (const float*)d_in[1];
    float* out = (float*)d_out;

    const size_t xcBytes = (size_t)XC_ELE * 2;         // 4,194,304
    ushort* xc = (ushort*)d_ws;

    if (ws_size >= xcBytes) {
        make_xc<<<32 * IN_HW, 256, 0, stream>>>(x, xc);
        lc_pos<<<NTILE, 128, 0, stream>>>(xc, w, out);
    } else {
        lc_naive<<<(32 * COUT * NPOS + 255) / 256, 256, 0, stream>>>(x, w, out);
    }
}